// Round 1
// baseline (435.994 us; speedup 1.0000x reference)
//
#include <hip/hip_runtime.h>
#include <hip/hip_bf16.h>

#define B_   2
#define N_   2048
#define DIM_ 1024
#define H_   16
#define DH_  64
#define SCALE_ 0.03125f  // DIM^-0.5 = 1/32

using bf16 = __hip_bfloat16;
typedef __bf16 bf16x8 __attribute__((ext_vector_type(8)));
typedef float  f32x4  __attribute__((ext_vector_type(4)));

__device__ __forceinline__ void gload16(const void* g, void* l) {
  __builtin_amdgcn_global_load_lds((const __attribute__((address_space(1))) void*)g,
                                   (__attribute__((address_space(3))) void*)l, 16, 0, 0);
}

// ---------------- casts ----------------
__global__ void cast_f32_bf16_k(const float* __restrict__ in, bf16* __restrict__ out, int n4) {
  int i = blockIdx.x * blockDim.x + threadIdx.x;
  if (i >= n4) return;
  float4 v = ((const float4*)in)[i];
  bf16 t[4] = {__float2bfloat16(v.x), __float2bfloat16(v.y),
               __float2bfloat16(v.z), __float2bfloat16(v.w)};
  ((ushort4*)out)[i] = *(ushort4*)t;
}

// out[C][R] (bf16) = transpose(in[R][C] f32)
__global__ void transpose_cast_k(const float* __restrict__ in, bf16* __restrict__ out,
                                 int R, int C) {
  __shared__ float tile[32][33];
  int tx = threadIdx.x & 31, ty = threadIdx.x >> 5;
  int r0 = blockIdx.y * 32, c0 = blockIdx.x * 32;
#pragma unroll
  for (int i = 0; i < 32; i += 8)
    tile[ty + i][tx] = in[(size_t)(r0 + ty + i) * C + c0 + tx];
  __syncthreads();
#pragma unroll
  for (int i = 0; i < 32; i += 8)
    out[(size_t)(c0 + ty + i) * R + r0 + tx] = __float2bfloat16(tile[tx][ty + i]);
}

// ---------------- GEMM: C[M,Ncols] = A[M,K] @ Bt[Ncols,K]^T ----------------
// EPI 0: scatter to q/k/v buffers (q scaled).  EPI 1: f32 out + bias.
template <int EPI>
__global__ __launch_bounds__(256) void gemm_bt_k(
    const bf16* __restrict__ A, const bf16* __restrict__ Bt,
    int M, int Ncols, int K,
    bf16* __restrict__ qb, bf16* __restrict__ kb, bf16* __restrict__ vt,
    float* __restrict__ Cout, const float* __restrict__ bias) {
  __shared__ bf16 As[128 * 32];
  __shared__ bf16 Bs[128 * 32];
  const int tid = threadIdx.x, lane = tid & 63, wid = tid >> 6;
  const int wr = wid >> 1, wc = wid & 1;
  const int m0 = blockIdx.y * 128, n0 = blockIdx.x * 128;
  const int l16 = lane & 15, lhi = lane >> 4;

  // staging: pre-swizzle the GLOBAL source block so linear-LDS + swizzled read works (rule 21)
  const int srow = lane >> 2;                        // row within 16-row chunk
  const int sblk = (lane & 3) ^ ((lane >> 3) & 3);   // source 16B-block (8 elems)
  // fragment-read swizzled block:
  const int rblk = lhi ^ ((l16 >> 1) & 3);

  f32x4 acc[4][4] = {};

  for (int kt = 0; kt < K; kt += 32) {
    __syncthreads();
#pragma unroll
    for (int c = 0; c < 2; ++c) {
      int ch = wid * 2 + c;
      int row = ch * 16 + srow;
      gload16(A + (size_t)(m0 + row) * K + kt + sblk * 8, (void*)(As + ch * 512 + lane * 8));
      gload16(Bt + (size_t)(n0 + row) * K + kt + sblk * 8, (void*)(Bs + ch * 512 + lane * 8));
    }
    __syncthreads();
    bf16x8 af[4], bfr[4];
#pragma unroll
    for (int m = 0; m < 4; ++m)
      af[m] = *(const bf16x8*)(As + (wr * 64 + m * 16 + l16) * 32 + rblk * 8);
#pragma unroll
    for (int n = 0; n < 4; ++n)
      bfr[n] = *(const bf16x8*)(Bs + (wc * 64 + n * 16 + l16) * 32 + rblk * 8);
#pragma unroll
    for (int m = 0; m < 4; ++m)
#pragma unroll
      for (int n = 0; n < 4; ++n)
        acc[m][n] = __builtin_amdgcn_mfma_f32_16x16x32_bf16(af[m], bfr[n], acc[m][n], 0, 0, 0);
  }

  // epilogue: D layout col=lane&15, row=(lane>>4)*4+reg  [verified m89]
#pragma unroll
  for (int m = 0; m < 4; ++m) {
    const int row = m0 + wr * 64 + m * 16 + lhi * 4;
#pragma unroll
    for (int n = 0; n < 4; ++n) {
      const int col = n0 + wc * 64 + n * 16 + l16;
#pragma unroll
      for (int r = 0; r < 4; ++r) {
        float v = acc[m][n][r];
        int rr = row + r;
        if (EPI == 0) {
          int b = rr >> 11, np = rr & (N_ - 1);
          if (col < DIM_) {  // Q (pre-scaled)
            int h = col >> 6, dh = col & 63;
            qb[(((size_t)b * H_ + h) * N_ + np) * DH_ + dh] = __float2bfloat16(v * SCALE_);
          } else if (col < 2 * DIM_) {  // K
            int c2 = col - DIM_, h = c2 >> 6, dh = c2 & 63;
            kb[(((size_t)b * H_ + h) * N_ + np) * DH_ + dh] = __float2bfloat16(v);
          } else {  // V transposed [B,H,DH,N]
            int c2 = col - 2 * DIM_, h = c2 >> 6, dh = c2 & 63;
            vt[(((size_t)b * H_ + h) * DH_ + dh) * N_ + np] = __float2bfloat16(v);
          }
        } else {
          Cout[(size_t)rr * Ncols + col] = v + bias[col];
        }
      }
    }
  }
}

// ---------------- flash attention ----------------
// grid (32 qtiles, B*H).  4 waves x 16 q-rows.  K/V straight from global (L2-fits).
__global__ __launch_bounds__(256) void attn_k(const bf16* __restrict__ qb,
                                              const bf16* __restrict__ kb,
                                              const bf16* __restrict__ vt,
                                              bf16* __restrict__ ob) {
  __shared__ bf16 P[4 * 16 * 64];
  const int tid = threadIdx.x, lane = tid & 63, w = tid >> 6;
  const int l16 = lane & 15, lhi = lane >> 4;
  const int bh = blockIdx.y, b = bh >> 4, h = bh & 15;
  const int qt = blockIdx.x;
  const int q0 = qt * 64 + w * 16;

  const bf16* qp = qb + ((size_t)bh * N_ + q0 + l16) * DH_ + lhi * 8;
  bf16x8 qa0 = *(const bf16x8*)qp;
  bf16x8 qa1 = *(const bf16x8*)(qp + 32);

  f32x4 o[4] = {};
  float mr[4] = {-1e30f, -1e30f, -1e30f, -1e30f};
  float lr[4] = {0.f, 0.f, 0.f, 0.f};
  char* Pw = (char*)(P + w * 16 * 64);

  for (int jt = 0; jt <= qt; ++jt) {
    const int j0 = jt * 64;
    f32x4 s[4];
#pragma unroll
    for (int jn = 0; jn < 4; ++jn) {
      const bf16* kp = kb + ((size_t)bh * N_ + j0 + jn * 16 + l16) * DH_ + lhi * 8;
      bf16x8 k0 = *(const bf16x8*)kp;
      bf16x8 k1 = *(const bf16x8*)(kp + 32);
      f32x4 t = {};
      t = __builtin_amdgcn_mfma_f32_16x16x32_bf16(qa0, k0, t, 0, 0, 0);
      t = __builtin_amdgcn_mfma_f32_16x16x32_bf16(qa1, k1, t, 0, 0, 0);
      s[jn] = t;
    }
    if (jt == qt) {  // diagonal tile: causal mask
#pragma unroll
      for (int jn = 0; jn < 4; ++jn) {
        int j = j0 + jn * 16 + l16;
#pragma unroll
        for (int r = 0; r < 4; ++r) {
          int i = q0 + lhi * 4 + r;
          if (j > i) s[jn][r] = -1e30f;
        }
      }
    }
    // row max (rows live on 16-lane groups; wave-parallel reduce)
    float pm[4];
#pragma unroll
    for (int r = 0; r < 4; ++r)
      pm[r] = fmaxf(fmaxf(s[0][r], s[1][r]), fmaxf(s[2][r], s[3][r]));
#pragma unroll
    for (int off = 1; off < 16; off <<= 1)
#pragma unroll
      for (int r = 0; r < 4; ++r) pm[r] = fmaxf(pm[r], __shfl_xor(pm[r], off, 64));
    float fac[4];
#pragma unroll
    for (int r = 0; r < 4; ++r) {
      float mn = fmaxf(mr[r], pm[r]);
      fac[r] = __expf(mr[r] - mn);
      mr[r] = mn;
    }
#pragma unroll
    for (int dn = 0; dn < 4; ++dn)
#pragma unroll
      for (int r = 0; r < 4; ++r) o[dn][r] *= fac[r];
    float rs[4] = {0.f, 0.f, 0.f, 0.f};
#pragma unroll
    for (int jn = 0; jn < 4; ++jn)
#pragma unroll
      for (int r = 0; r < 4; ++r) {
        float p = __expf(s[jn][r] - mr[r]);
        s[jn][r] = p;
        rs[r] += p;
      }
#pragma unroll
    for (int off = 1; off < 16; off <<= 1)
#pragma unroll
      for (int r = 0; r < 4; ++r) rs[r] += __shfl_xor(rs[r], off, 64);
#pragma unroll
    for (int r = 0; r < 4; ++r) lr[r] = lr[r] * fac[r] + rs[r];

    // P -> LDS, XOR-swizzled (G4: byte ^= (row&7)<<4), then read as A-fragments
#pragma unroll
    for (int jn = 0; jn < 4; ++jn)
#pragma unroll
      for (int r = 0; r < 4; ++r) {
        int row = lhi * 4 + r;
        int cb = (jn * 16 + l16) * 2;
        *(bf16*)(Pw + row * 128 + (cb ^ ((row & 7) << 4))) = __float2bfloat16(s[jn][r]);
      }
    bf16x8 pa0 = *(const bf16x8*)(Pw + l16 * 128 + ((lhi * 16) ^ ((l16 & 7) << 4)));
    bf16x8 pa1 = *(const bf16x8*)(Pw + l16 * 128 + ((64 + lhi * 16) ^ ((l16 & 7) << 4)));

#pragma unroll
    for (int dn = 0; dn < 4; ++dn) {
      const bf16* vp = vt + ((size_t)bh * DH_ + dn * 16 + l16) * N_ + j0 + lhi * 8;
      bf16x8 v0 = *(const bf16x8*)vp;
      bf16x8 v1 = *(const bf16x8*)(vp + 32);
      o[dn] = __builtin_amdgcn_mfma_f32_16x16x32_bf16(pa0, v0, o[dn], 0, 0, 0);
      o[dn] = __builtin_amdgcn_mfma_f32_16x16x32_bf16(pa1, v1, o[dn], 0, 0, 0);
    }
  }
#pragma unroll
  for (int dn = 0; dn < 4; ++dn)
#pragma unroll
    for (int r = 0; r < 4; ++r) {
      int nrow = q0 + lhi * 4 + r;
      float v = o[dn][r] / lr[r];
      ob[((size_t)b * N_ + nrow) * DIM_ + h * DH_ + dn * 16 + l16] = __float2bfloat16(v);
    }
}

// ---------------- launcher ----------------
extern "C" void kernel_launch(void* const* d_in, const int* in_sizes, int n_in,
                              void* d_out, int out_size, void* d_ws, size_t ws_size,
                              hipStream_t stream) {
  const float* x   = (const float*)d_in[0];
  // d_in[1] = causal mask (tril) — implemented analytically
  const float* Wq  = (const float*)d_in[2];
  const float* Wkv = (const float*)d_in[3];
  const float* Wo  = (const float*)d_in[4];
  const float* bo  = (const float*)d_in[5];
  float* out = (float*)d_out;
  char* ws = (char*)d_ws;
  const size_t MB = 1u << 20;
  bf16* xb   = (bf16*)(ws + 0 * MB);   // [4096,1024]
  bf16* qb   = (bf16*)(ws + 8 * MB);   // [B,H,N,DH]
  bf16* kb   = (bf16*)(ws + 16 * MB);  // [B,H,N,DH]
  bf16* vt   = (bf16*)(ws + 24 * MB);  // [B,H,DH,N]
  bf16* ab   = (bf16*)(ws + 32 * MB);  // [B,N,DIM]
  bf16* wqt  = (bf16*)(ws + 40 * MB);  // [1024,1024]   (contiguous with wkvt!)
  bf16* wkvt = (bf16*)(ws + 42 * MB);  // [2048,1024]
  bf16* wot  = (bf16*)(ws + 46 * MB);  // [1024,1024]

  cast_f32_bf16_k<<<dim3((B_ * N_ * DIM_) / 4 / 256), dim3(256), 0, stream>>>(
      x, xb, (B_ * N_ * DIM_) / 4);
  transpose_cast_k<<<dim3(32, 32), dim3(256), 0, stream>>>(Wq, wqt, DIM_, DIM_);
  transpose_cast_k<<<dim3(64, 32), dim3(256), 0, stream>>>(Wkv, wkvt, DIM_, 2 * DIM_);
  transpose_cast_k<<<dim3(32, 32), dim3(256), 0, stream>>>(Wo, wot, DIM_, DIM_);

  gemm_bt_k<0><<<dim3(24, 32), dim3(256), 0, stream>>>(
      xb, wqt, B_ * N_, 3 * DIM_, DIM_, qb, kb, vt, nullptr, nullptr);
  attn_k<<<dim3(32, B_ * H_), dim3(256), 0, stream>>>(qb, kb, vt, ab);
  gemm_bt_k<1><<<dim3(8, 32), dim3(256), 0, stream>>>(
      ab, wot, B_ * N_, DIM_, DIM_, nullptr, nullptr, nullptr, out, bo);
}

// Round 4
// 209.766 us; speedup vs baseline: 2.0785x; 2.0785x over previous
//
#include <hip/hip_runtime.h>
#include <hip/hip_bf16.h>

#define B_   2
#define N_   2048
#define DIM_ 1024
#define H_   16
#define DH_  64
#define SCALE_ 0.03125f  // DIM^-0.5 = 1/32

using bf16 = __hip_bfloat16;
typedef __bf16 bf16x8 __attribute__((ext_vector_type(8)));
typedef float  f32x4  __attribute__((ext_vector_type(4)));

__device__ __forceinline__ void gload16(const void* g, void* l) {
  __builtin_amdgcn_global_load_lds((const __attribute__((address_space(1))) void*)g,
                                   (__attribute__((address_space(3))) void*)l, 16, 0, 0);
}

// ---------------- casts ----------------
__global__ void cast_f32_bf16_k(const float* __restrict__ in, bf16* __restrict__ out, int n4) {
  int i = blockIdx.x * blockDim.x + threadIdx.x;
  if (i >= n4) return;
  float4 v = ((const float4*)in)[i];
  bf16 t[4] = {__float2bfloat16(v.x), __float2bfloat16(v.y),
               __float2bfloat16(v.z), __float2bfloat16(v.w)};
  ((ushort4*)out)[i] = *(ushort4*)t;
}

// out[C][R] (bf16) = transpose(in[R][C] f32)
__global__ void transpose_cast_k(const float* __restrict__ in, bf16* __restrict__ out,
                                 int R, int C) {
  __shared__ float tile[32][33];
  int tx = threadIdx.x & 31, ty = threadIdx.x >> 5;
  int r0 = blockIdx.y * 32, c0 = blockIdx.x * 32;
#pragma unroll
  for (int i = 0; i < 32; i += 8)
    tile[ty + i][tx] = in[(size_t)(r0 + ty + i) * C + c0 + tx];
  __syncthreads();
#pragma unroll
  for (int i = 0; i < 32; i += 8)
    out[(size_t)(c0 + ty + i) * R + r0 + tx] = __float2bfloat16(tile[tx][ty + i]);
}

// ---------------- GEMM: C[M,Ncols] = A[M,K] @ Bt[Ncols,K]^T ----------------
template <int EPI>
__global__ __launch_bounds__(256) void gemm_bt_k(
    const bf16* __restrict__ A, const bf16* __restrict__ Bt,
    int M, int Ncols, int K,
    bf16* __restrict__ qb, bf16* __restrict__ kb, bf16* __restrict__ vt,
    float* __restrict__ Cout, const float* __restrict__ bias) {
  __shared__ bf16 As[128 * 32];
  __shared__ bf16 Bs[128 * 32];
  const int tid = threadIdx.x, lane = tid & 63, wid = tid >> 6;
  const int wr = wid >> 1, wc = wid & 1;
  const int m0 = blockIdx.y * 128, n0 = blockIdx.x * 128;
  const int l16 = lane & 15, lhi = lane >> 4;

  const int srow = lane >> 2;
  const int sblk = (lane & 3) ^ ((lane >> 3) & 3);
  const int rblk = lhi ^ ((l16 >> 1) & 3);

  f32x4 acc[4][4] = {};

  for (int kt = 0; kt < K; kt += 32) {
    __syncthreads();
#pragma unroll
    for (int c = 0; c < 2; ++c) {
      int ch = wid * 2 + c;
      int row = ch * 16 + srow;
      gload16(A + (size_t)(m0 + row) * K + kt + sblk * 8, (void*)(As + ch * 512 + lane * 8));
      gload16(Bt + (size_t)(n0 + row) * K + kt + sblk * 8, (void*)(Bs + ch * 512 + lane * 8));
    }
    __syncthreads();
    bf16x8 af[4], bfr[4];
#pragma unroll
    for (int m = 0; m < 4; ++m)
      af[m] = *(const bf16x8*)(As + (wr * 64 + m * 16 + l16) * 32 + rblk * 8);
#pragma unroll
    for (int n = 0; n < 4; ++n)
      bfr[n] = *(const bf16x8*)(Bs + (wc * 64 + n * 16 + l16) * 32 + rblk * 8);
#pragma unroll
    for (int m = 0; m < 4; ++m)
#pragma unroll
      for (int n = 0; n < 4; ++n)
        acc[m][n] = __builtin_amdgcn_mfma_f32_16x16x32_bf16(af[m], bfr[n], acc[m][n], 0, 0, 0);
  }

#pragma unroll
  for (int m = 0; m < 4; ++m) {
    const int row = m0 + wr * 64 + m * 16 + lhi * 4;
#pragma unroll
    for (int n = 0; n < 4; ++n) {
      const int col = n0 + wc * 64 + n * 16 + l16;
#pragma unroll
      for (int r = 0; r < 4; ++r) {
        float v = acc[m][n][r];
        int rr = row + r;
        if (EPI == 0) {
          int b = rr >> 11, np = rr & (N_ - 1);
          if (col < DIM_) {
            int h = col >> 6, dh = col & 63;
            qb[(((size_t)b * H_ + h) * N_ + np) * DH_ + dh] = __float2bfloat16(v * SCALE_);
          } else if (col < 2 * DIM_) {
            int c2 = col - DIM_, h = c2 >> 6, dh = c2 & 63;
            kb[(((size_t)b * H_ + h) * N_ + np) * DH_ + dh] = __float2bfloat16(v);
          } else {
            int c2 = col - 2 * DIM_, h = c2 >> 6, dh = c2 & 63;
            vt[(((size_t)b * H_ + h) * DH_ + dh) * N_ + np] = __float2bfloat16(v);
          }
        } else {
          Cout[(size_t)rr * Ncols + col] = v + bias[col];
        }
      }
    }
  }
}

// ---------------- flash attention (v2) ----------------
// Swapped QK^T (S^T = K·Q) -> lane-local row stats.  K/V staged in LDS via
// global_load_lds (double-buffered, 2-phase), XOR-swizzled reads (rule 21:
// linear LDS dest + inverse-swizzled global source).  Flat grid: descending
// qt starts heavy blocks first; bh%8 pins each head-pair to one XCD's L2.
// LDS = 40960 B/block -> exactly 4 blocks/CU (163840 B = 160 KiB).
__global__ __launch_bounds__(256, 4) void attn_k(const bf16* __restrict__ qb,
                                                 const bf16* __restrict__ kb,
                                                 const bf16* __restrict__ vt,
                                                 bf16* __restrict__ ob) {
  __shared__ bf16 KV[2][2][4096];  // [buf][K=0/V=1][64 rows x 64 cols]
  __shared__ bf16 P[4][1024];      // per-wave 16 x 64 P tile
  const int tid = threadIdx.x, lane = tid & 63, w = tid >> 6;
  const int l16 = lane & 15, lhi = lane >> 4;
  const int bh = blockIdx.x & 31, b = bh >> 4, h = bh & 15;
  const int qt = 31 - (blockIdx.x >> 5);
  const int q0 = qt * 64 + w * 16;
  const int swz = (l16 & 7) << 4;

  // staging geometry (inverse-swizzled global source, linear LDS dest)
  const int srow = tid >> 3;                                // 0..31
  const int ssc = ((tid & 7) * 16) ^ ((srow & 7) << 4);     // source byte col
  const char* kbase = (const char*)kb + ((size_t)bh * N_) * 128;
  const char* vbase = (const char*)vt + ((size_t)bh * DH_) * 4096;

#define STAGE(buf, j0s)                                                          \
  {                                                                              \
    _Pragma("unroll") for (int c = 0; c < 2; ++c) {                              \
      int ro = c * 32 + srow;                                                    \
      gload16(kbase + (size_t)((j0s) + ro) * 128 + ssc,                          \
              (char*)&KV[buf][0][0] + c * 4096 + tid * 16);                      \
      gload16(vbase + (size_t)ro * 4096 + (j0s) * 2 + ssc,                       \
              (char*)&KV[buf][1][0] + c * 4096 + tid * 16);                      \
    }                                                                            \
  }

  // Q as B-operand: lane holds col=l16 (q-row), k=dh slice lhi*8..+8
  const bf16* qp = qb + ((size_t)bh * N_ + q0 + l16) * DH_ + lhi * 8;
  bf16x8 qa0 = *(const bf16x8*)qp;
  bf16x8 qa1 = *(const bf16x8*)(qp + 32);

  f32x4 o[4] = {};
  float mr = -1e30f, lr = 0.f;
  char* Pw = (char*)&P[w][0];

  STAGE(0, 0);
  __syncthreads();

  for (int jt = 0; jt <= qt; ++jt) {
    const int cur = jt & 1;
    if (jt < qt) STAGE(cur ^ 1, (jt + 1) * 64);

    const char* Kb = (const char*)&KV[cur][0][0];
    const char* Vb = (const char*)&KV[cur][1][0];
    const bool diag = (jt == qt);
    const int jnmax = diag ? (w + 1) : 4;

    // S^T = K·Q : lane holds s[jn][r] = S[q0+l16][jt*64 + jn*16 + lhi*4 + r]
    f32x4 s[4];
#pragma unroll
    for (int jn = 0; jn < 4; ++jn) {
      if (jn < jnmax) {
        const char* kr = Kb + (jn * 16 + l16) * 128;
        bf16x8 k0 = *(const bf16x8*)(kr + ((lhi * 16) ^ swz));
        bf16x8 k1 = *(const bf16x8*)(kr + ((64 + lhi * 16) ^ swz));
        f32x4 t = {};
        t = __builtin_amdgcn_mfma_f32_16x16x32_bf16(k0, qa0, t, 0, 0, 0);
        t = __builtin_amdgcn_mfma_f32_16x16x32_bf16(k1, qa1, t, 0, 0, 0);
        s[jn] = t;
      } else {
        s[jn] = f32x4{-1e30f, -1e30f, -1e30f, -1e30f};
      }
    }
    if (diag) {
#pragma unroll
      for (int jn = 0; jn < 4; ++jn)
#pragma unroll
        for (int r = 0; r < 4; ++r)
          if (jn * 16 + lhi * 4 + r > w * 16 + l16) s[jn][r] = -1e30f;
    }

    // row stats: in-lane over 16 regs, then reduce across the 4 lhi groups
    float pm = s[0][0];
#pragma unroll
    for (int jn = 0; jn < 4; ++jn)
#pragma unroll
      for (int r = 0; r < 4; ++r) pm = fmaxf(pm, s[jn][r]);
    pm = fmaxf(pm, __shfl_xor(pm, 16, 64));
    pm = fmaxf(pm, __shfl_xor(pm, 32, 64));
    float mn = fmaxf(mr, pm);
    float fac = __expf(mr - mn);
    mr = mn;
    float rs = 0.f;
#pragma unroll
    for (int jn = 0; jn < 4; ++jn) {
      bf16 pk[4];
#pragma unroll
      for (int r = 0; r < 4; ++r) {
        float p = __expf(s[jn][r] - mr);
        rs += p;
        pk[r] = __float2bfloat16(p);
      }
      // packed P write: row l16, cols jn*16+lhi*4..+3 (8B, swizzled)
      *(short4*)(Pw + l16 * 128 + ((jn * 32 + lhi * 8) ^ swz)) = *(short4*)pk;
    }
    rs += __shfl_xor(rs, 16, 64);
    rs += __shfl_xor(rs, 32, 64);
    lr = lr * fac + rs;

    // rescale O (output rows live at lhi*4+r -> broadcast fac from lane row)
    float fr[4];
#pragma unroll
    for (int r = 0; r < 4; ++r) fr[r] = __shfl(fac, lhi * 4 + r, 64);
#pragma unroll
    for (int dn = 0; dn < 4; ++dn)
#pragma unroll
      for (int r = 0; r < 4; ++r) o[dn][r] *= fr[r];

    // P as A-operand: lane reads row l16, k slice lhi*8..+8 (swizzled)
    bf16x8 pa0 = *(const bf16x8*)(Pw + l16 * 128 + ((lhi * 16) ^ swz));
    bf16x8 pa1 = *(const bf16x8*)(Pw + l16 * 128 + ((64 + lhi * 16) ^ swz));

#pragma unroll
    for (int dn = 0; dn < 4; ++dn) {
      const char* vr = Vb + (dn * 16 + l16) * 128;
      bf16x8 v0 = *(const bf16x8*)(vr + ((lhi * 16) ^ swz));
      bf16x8 v1 = *(const bf16x8*)(vr + ((64 + lhi * 16) ^ swz));
      o[dn] = __builtin_amdgcn_mfma_f32_16x16x32_bf16(pa0, v0, o[dn], 0, 0, 0);
      o[dn] = __builtin_amdgcn_mfma_f32_16x16x32_bf16(pa1, v1, o[dn], 0, 0, 0);
    }
    __syncthreads();
  }

  float lf[4];
#pragma unroll
  for (int r = 0; r < 4; ++r) lf[r] = __shfl(lr, lhi * 4 + r, 64);
#pragma unroll
  for (int dn = 0; dn < 4; ++dn)
#pragma unroll
    for (int r = 0; r < 4; ++r) {
      int nrow = q0 + lhi * 4 + r;
      float v = o[dn][r] / lf[r];
      ob[((size_t)b * N_ + nrow) * DIM_ + h * DH_ + dn * 16 + l16] = __float2bfloat16(v);
    }
#undef STAGE
}

// ---------------- launcher ----------------
extern "C" void kernel_launch(void* const* d_in, const int* in_sizes, int n_in,
                              void* d_out, int out_size, void* d_ws, size_t ws_size,
                              hipStream_t stream) {
  const float* x   = (const float*)d_in[0];
  const float* Wq  = (const float*)d_in[2];
  const float* Wkv = (const float*)d_in[3];
  const float* Wo  = (const float*)d_in[4];
  const float* bo  = (const float*)d_in[5];
  float* out = (float*)d_out;
  char* ws = (char*)d_ws;
  const size_t MB = 1u << 20;
  bf16* xb   = (bf16*)(ws + 0 * MB);
  bf16* qb   = (bf16*)(ws + 8 * MB);
  bf16* kb   = (bf16*)(ws + 16 * MB);
  bf16* vt   = (bf16*)(ws + 24 * MB);
  bf16* ab   = (bf16*)(ws + 32 * MB);
  bf16* wqt  = (bf16*)(ws + 40 * MB);
  bf16* wkvt = (bf16*)(ws + 42 * MB);
  bf16* wot  = (bf16*)(ws + 46 * MB);

  cast_f32_bf16_k<<<dim3((B_ * N_ * DIM_) / 4 / 256), dim3(256), 0, stream>>>(
      x, xb, (B_ * N_ * DIM_) / 4);
  transpose_cast_k<<<dim3(32, 32), dim3(256), 0, stream>>>(Wq, wqt, DIM_, DIM_);
  transpose_cast_k<<<dim3(64, 32), dim3(256), 0, stream>>>(Wkv, wkvt, DIM_, 2 * DIM_);
  transpose_cast_k<<<dim3(32, 32), dim3(256), 0, stream>>>(Wo, wot, DIM_, DIM_);

  gemm_bt_k<0><<<dim3(24, 32), dim3(256), 0, stream>>>(
      xb, wqt, B_ * N_, 3 * DIM_, DIM_, qb, kb, vt, nullptr, nullptr);
  attn_k<<<dim3(1024), dim3(256), 0, stream>>>(qb, kb, vt, ab);
  gemm_bt_k<1><<<dim3(8, 32), dim3(256), 0, stream>>>(
      ab, wot, B_ * N_, DIM_, DIM_, nullptr, nullptr, nullptr, out, bo);
}

// Round 5
// 197.666 us; speedup vs baseline: 2.2057x; 1.0612x over previous
//
#include <hip/hip_runtime.h>
#include <hip/hip_bf16.h>

#define B_   2
#define N_   2048
#define DIM_ 1024
#define H_   16
#define DH_  64
#define SCALE_ 0.03125f  // DIM^-0.5 = 1/32

using bf16 = __hip_bfloat16;
typedef __bf16 bf16x8 __attribute__((ext_vector_type(8)));
typedef float  f32x4  __attribute__((ext_vector_type(4)));

__device__ __forceinline__ void gload16(const void* g, void* l) {
  __builtin_amdgcn_global_load_lds((const __attribute__((address_space(1))) void*)g,
                                   (__attribute__((address_space(3))) void*)l, 16, 0, 0);
}

// ---------------- fused prologue ----------------
// blocks 0..4095: weight transpose+cast (0..1023 Wq, 1024..3071 Wkv, 3072..4095 Wo)
// blocks 4096..8191: linear cast of x (float4 -> 4x bf16 each thread)
__global__ __launch_bounds__(256) void prep_k(
    const float* __restrict__ x, const float* __restrict__ Wq,
    const float* __restrict__ Wkv, const float* __restrict__ Wo,
    bf16* __restrict__ xb, bf16* __restrict__ wqt,
    bf16* __restrict__ wkvt, bf16* __restrict__ wot) {
  __shared__ float tile[32][33];
  const int blk = blockIdx.x;
  if (blk < 4096) {
    const float* in; bf16* out; int C, bx, by;
    if (blk < 1024)      { in = Wq;  out = wqt;  C = 1024; bx = blk & 31; by = blk >> 5; }
    else if (blk < 3072) { int l = blk - 1024; in = Wkv; out = wkvt; C = 2048; bx = l & 63; by = l >> 6; }
    else                 { int l = blk - 3072; in = Wo;  out = wot;  C = 1024; bx = l & 31; by = l >> 5; }
    const int R = 1024;
    int tx = threadIdx.x & 31, ty = threadIdx.x >> 5;
    int r0 = by * 32, c0 = bx * 32;
#pragma unroll
    for (int i = 0; i < 32; i += 8)
      tile[ty + i][tx] = in[(size_t)(r0 + ty + i) * C + c0 + tx];
    __syncthreads();
#pragma unroll
    for (int i = 0; i < 32; i += 8)
      out[(size_t)(c0 + ty + i) * R + r0 + tx] = __float2bfloat16(tile[tx][ty + i]);
  } else {
    int i = (blk - 4096) * 256 + threadIdx.x;  // float4 index; total 1048576
    float4 v = ((const float4*)x)[i];
    bf16 t[4] = {__float2bfloat16(v.x), __float2bfloat16(v.y),
                 __float2bfloat16(v.z), __float2bfloat16(v.w)};
    ((ushort4*)xb)[i] = *(ushort4*)t;
  }
}

// ---------------- GEMM: C[M,Ncols] = A[M,K] @ Bt[Ncols,K]^T ----------------
// 2-phase double-buffered (T3 minimum): issue next tile's global_load_lds
// BEFORE consuming current tile; single barrier per K-step.
template <int EPI>
__global__ __launch_bounds__(256) void gemm_bt_k(
    const bf16* __restrict__ A, const bf16* __restrict__ Bt,
    int M, int Ncols, int K,
    bf16* __restrict__ qb, bf16* __restrict__ kb, bf16* __restrict__ vt,
    float* __restrict__ Cout, const float* __restrict__ bias) {
  __shared__ bf16 As[2][128 * 32];
  __shared__ bf16 Bs[2][128 * 32];
  const int tid = threadIdx.x, lane = tid & 63, wid = tid >> 6;
  const int wr = wid >> 1, wc = wid & 1;
  const int m0 = blockIdx.y * 128, n0 = blockIdx.x * 128;
  const int l16 = lane & 15, lhi = lane >> 4;

  const int srow = lane >> 2;
  const int sblk = (lane & 3) ^ ((lane >> 3) & 3);
  const int rblk = lhi ^ ((l16 >> 1) & 3);

#define GSTAGE(buf, kt)                                                              \
  {                                                                                  \
    _Pragma("unroll") for (int c = 0; c < 2; ++c) {                                  \
      int ch = wid * 2 + c;                                                          \
      int row = ch * 16 + srow;                                                      \
      gload16(A + (size_t)(m0 + row) * K + (kt) + sblk * 8,                          \
              (void*)(As[buf] + ch * 512 + lane * 8));                               \
      gload16(Bt + (size_t)(n0 + row) * K + (kt) + sblk * 8,                         \
              (void*)(Bs[buf] + ch * 512 + lane * 8));                               \
    }                                                                                \
  }

  f32x4 acc[4][4] = {};
  const int nk = K >> 5;

  GSTAGE(0, 0);
  __syncthreads();

  for (int kt = 0; kt < nk; ++kt) {
    const int cur = kt & 1;
    if (kt + 1 < nk) GSTAGE(cur ^ 1, (kt + 1) * 32);

    bf16x8 af[4], bfr[4];
#pragma unroll
    for (int m = 0; m < 4; ++m)
      af[m] = *(const bf16x8*)(As[cur] + (wr * 64 + m * 16 + l16) * 32 + rblk * 8);
#pragma unroll
    for (int n = 0; n < 4; ++n)
      bfr[n] = *(const bf16x8*)(Bs[cur] + (wc * 64 + n * 16 + l16) * 32 + rblk * 8);
#pragma unroll
    for (int m = 0; m < 4; ++m)
#pragma unroll
      for (int n = 0; n < 4; ++n)
        acc[m][n] = __builtin_amdgcn_mfma_f32_16x16x32_bf16(af[m], bfr[n], acc[m][n], 0, 0, 0);
    __syncthreads();
  }
#undef GSTAGE

#pragma unroll
  for (int m = 0; m < 4; ++m) {
    const int row = m0 + wr * 64 + m * 16 + lhi * 4;
#pragma unroll
    for (int n = 0; n < 4; ++n) {
      const int col = n0 + wc * 64 + n * 16 + l16;
#pragma unroll
      for (int r = 0; r < 4; ++r) {
        float v = acc[m][n][r];
        int rr = row + r;
        if (EPI == 0) {
          int b = rr >> 11, np = rr & (N_ - 1);
          if (col < DIM_) {
            int h = col >> 6, dh = col & 63;
            qb[(((size_t)b * H_ + h) * N_ + np) * DH_ + dh] = __float2bfloat16(v * SCALE_);
          } else if (col < 2 * DIM_) {
            int c2 = col - DIM_, h = c2 >> 6, dh = c2 & 63;
            kb[(((size_t)b * H_ + h) * N_ + np) * DH_ + dh] = __float2bfloat16(v);
          } else {
            int c2 = col - 2 * DIM_, h = c2 >> 6, dh = c2 & 63;
            vt[(((size_t)b * H_ + h) * DH_ + dh) * N_ + np] = __float2bfloat16(v);
          }
        } else {
          Cout[(size_t)rr * Ncols + col] = v + bias[col];
        }
      }
    }
  }
}

// ---------------- flash attention (v2, unchanged from round 4) ----------------
__global__ __launch_bounds__(256, 4) void attn_k(const bf16* __restrict__ qb,
                                                 const bf16* __restrict__ kb,
                                                 const bf16* __restrict__ vt,
                                                 bf16* __restrict__ ob) {
  __shared__ bf16 KV[2][2][4096];  // [buf][K=0/V=1][64 rows x 64 cols]
  __shared__ bf16 P[4][1024];      // per-wave 16 x 64 P tile
  const int tid = threadIdx.x, lane = tid & 63, w = tid >> 6;
  const int l16 = lane & 15, lhi = lane >> 4;
  const int bh = blockIdx.x & 31, b = bh >> 4, h = bh & 15;
  const int qt = 31 - (blockIdx.x >> 5);
  const int q0 = qt * 64 + w * 16;
  const int swz = (l16 & 7) << 4;

  const int srow = tid >> 3;
  const int ssc = ((tid & 7) * 16) ^ ((srow & 7) << 4);
  const char* kbase = (const char*)kb + ((size_t)bh * N_) * 128;
  const char* vbase = (const char*)vt + ((size_t)bh * DH_) * 4096;

#define STAGE(buf, j0s)                                                          \
  {                                                                              \
    _Pragma("unroll") for (int c = 0; c < 2; ++c) {                              \
      int ro = c * 32 + srow;                                                    \
      gload16(kbase + (size_t)((j0s) + ro) * 128 + ssc,                          \
              (char*)&KV[buf][0][0] + c * 4096 + tid * 16);                      \
      gload16(vbase + (size_t)ro * 4096 + (j0s) * 2 + ssc,                       \
              (char*)&KV[buf][1][0] + c * 4096 + tid * 16);                      \
    }                                                                            \
  }

  const bf16* qp = qb + ((size_t)bh * N_ + q0 + l16) * DH_ + lhi * 8;
  bf16x8 qa0 = *(const bf16x8*)qp;
  bf16x8 qa1 = *(const bf16x8*)(qp + 32);

  f32x4 o[4] = {};
  float mr = -1e30f, lr = 0.f;
  char* Pw = (char*)&P[w][0];

  STAGE(0, 0);
  __syncthreads();

  for (int jt = 0; jt <= qt; ++jt) {
    const int cur = jt & 1;
    if (jt < qt) STAGE(cur ^ 1, (jt + 1) * 64);

    const char* Kb = (const char*)&KV[cur][0][0];
    const char* Vb = (const char*)&KV[cur][1][0];
    const bool diag = (jt == qt);
    const int jnmax = diag ? (w + 1) : 4;

    f32x4 s[4];
#pragma unroll
    for (int jn = 0; jn < 4; ++jn) {
      if (jn < jnmax) {
        const char* kr = Kb + (jn * 16 + l16) * 128;
        bf16x8 k0 = *(const bf16x8*)(kr + ((lhi * 16) ^ swz));
        bf16x8 k1 = *(const bf16x8*)(kr + ((64 + lhi * 16) ^ swz));
        f32x4 t = {};
        t = __builtin_amdgcn_mfma_f32_16x16x32_bf16(k0, qa0, t, 0, 0, 0);
        t = __builtin_amdgcn_mfma_f32_16x16x32_bf16(k1, qa1, t, 0, 0, 0);
        s[jn] = t;
      } else {
        s[jn] = f32x4{-1e30f, -1e30f, -1e30f, -1e30f};
      }
    }
    if (diag) {
#pragma unroll
      for (int jn = 0; jn < 4; ++jn)
#pragma unroll
        for (int r = 0; r < 4; ++r)
          if (jn * 16 + lhi * 4 + r > w * 16 + l16) s[jn][r] = -1e30f;
    }

    float pm = s[0][0];
#pragma unroll
    for (int jn = 0; jn < 4; ++jn)
#pragma unroll
      for (int r = 0; r < 4; ++r) pm = fmaxf(pm, s[jn][r]);
    pm = fmaxf(pm, __shfl_xor(pm, 16, 64));
    pm = fmaxf(pm, __shfl_xor(pm, 32, 64));
    float mn = fmaxf(mr, pm);
    float fac = __expf(mr - mn);
    mr = mn;
    float rs = 0.f;
#pragma unroll
    for (int jn = 0; jn < 4; ++jn) {
      bf16 pk[4];
#pragma unroll
      for (int r = 0; r < 4; ++r) {
        float p = __expf(s[jn][r] - mr);
        rs += p;
        pk[r] = __float2bfloat16(p);
      }
      *(short4*)(Pw + l16 * 128 + ((jn * 32 + lhi * 8) ^ swz)) = *(short4*)pk;
    }
    rs += __shfl_xor(rs, 16, 64);
    rs += __shfl_xor(rs, 32, 64);
    lr = lr * fac + rs;

    float fr[4];
#pragma unroll
    for (int r = 0; r < 4; ++r) fr[r] = __shfl(fac, lhi * 4 + r, 64);
#pragma unroll
    for (int dn = 0; dn < 4; ++dn)
#pragma unroll
      for (int r = 0; r < 4; ++r) o[dn][r] *= fr[r];

    bf16x8 pa0 = *(const bf16x8*)(Pw + l16 * 128 + ((lhi * 16) ^ swz));
    bf16x8 pa1 = *(const bf16x8*)(Pw + l16 * 128 + ((64 + lhi * 16) ^ swz));

#pragma unroll
    for (int dn = 0; dn < 4; ++dn) {
      const char* vr = Vb + (dn * 16 + l16) * 128;
      bf16x8 v0 = *(const bf16x8*)(vr + ((lhi * 16) ^ swz));
      bf16x8 v1 = *(const bf16x8*)(vr + ((64 + lhi * 16) ^ swz));
      o[dn] = __builtin_amdgcn_mfma_f32_16x16x32_bf16(pa0, v0, o[dn], 0, 0, 0);
      o[dn] = __builtin_amdgcn_mfma_f32_16x16x32_bf16(pa1, v1, o[dn], 0, 0, 0);
    }
    __syncthreads();
  }

  float lf[4];
#pragma unroll
  for (int r = 0; r < 4; ++r) lf[r] = __shfl(lr, lhi * 4 + r, 64);
#pragma unroll
  for (int dn = 0; dn < 4; ++dn)
#pragma unroll
    for (int r = 0; r < 4; ++r) {
      int nrow = q0 + lhi * 4 + r;
      float v = o[dn][r] / lf[r];
      ob[((size_t)b * N_ + nrow) * DIM_ + h * DH_ + dn * 16 + l16] = __float2bfloat16(v);
    }
#undef STAGE
}

// ---------------- launcher ----------------
extern "C" void kernel_launch(void* const* d_in, const int* in_sizes, int n_in,
                              void* d_out, int out_size, void* d_ws, size_t ws_size,
                              hipStream_t stream) {
  const float* x   = (const float*)d_in[0];
  const float* Wq  = (const float*)d_in[2];
  const float* Wkv = (const float*)d_in[3];
  const float* Wo  = (const float*)d_in[4];
  const float* bo  = (const float*)d_in[5];
  float* out = (float*)d_out;
  char* ws = (char*)d_ws;
  const size_t MB = 1u << 20;
  bf16* xb   = (bf16*)(ws + 0 * MB);
  bf16* qb   = (bf16*)(ws + 8 * MB);
  bf16* kb   = (bf16*)(ws + 16 * MB);
  bf16* vt   = (bf16*)(ws + 24 * MB);
  bf16* ab   = (bf16*)(ws + 32 * MB);
  bf16* wqt  = (bf16*)(ws + 40 * MB);
  bf16* wkvt = (bf16*)(ws + 42 * MB);
  bf16* wot  = (bf16*)(ws + 46 * MB);

  prep_k<<<dim3(8192), dim3(256), 0, stream>>>(x, Wq, Wkv, Wo, xb, wqt, wkvt, wot);

  gemm_bt_k<0><<<dim3(24, 32), dim3(256), 0, stream>>>(
      xb, wqt, B_ * N_, 3 * DIM_, DIM_, qb, kb, vt, nullptr, nullptr);
  attn_k<<<dim3(1024), dim3(256), 0, stream>>>(qb, kb, vt, ab);
  gemm_bt_k<1><<<dim3(8, 32), dim3(256), 0, stream>>>(
      ab, wot, B_ * N_, DIM_, DIM_, nullptr, nullptr, nullptr, out, bo);
}